// Round 19
// baseline (38.921 us; speedup 1.0000x reference)
//
#include <hip/hip_runtime.h>
#include <math.h>

// Problem constants (fixed by setup_inputs)
constexpr int N    = 4;
constexpr int C    = 16;
constexpr int Hin  = 288;
constexpr int Win  = 1216;
constexpr int Hout = 800;
constexpr int Wout = 400;
constexpr int PIX_PER_N = Hout * Wout;       // 320000
constexpr int CH_STRIDE = Hin * Win;         // 350208
constexpr int TOTAL = N * Hout * Wout;       // 1,280,000
constexpr int HALF  = TOTAL / 2;             // 640,000
constexpr int BLK   = 512;                   // 8 waves per workgroup slot

// Base-grid constants (exact reference f32 values; see round-6 derivation).
constexpr double grd = 0.05 * (800.0 / (double)Hout);        // 0.05 (f64)
constexpr float  GR  = (float)grd;                            // f32(0.05)
constexpr float  CX0 = (float)(-10.0 + grd / 2.0);            // f32(-9.975)
constexpr float  CY0 = (float)( 46.0 - grd / 2.0);            // f32(45.975)

// Register barrier: keeps ops separately rounded exactly where the numpy
// reference's ufuncs are separately rounded (correctness-critical near the
// g2~0 projective singularity). Coordinate chain ONLY.
__device__ __forceinline__ float fbar(float x) {
    asm volatile("" : "+v"(x));
    return x;
}

struct Samp {
    int   lb0, lb1;           // clamped dwordx2 load bases (row y0 / y1)
    bool  hi0, hi1, xpair;    // corner-select flags
    float w00, w01, w10, w11; // bilinear weights
};

// Bit-exact coordinate chain (verified round 6: flavor-F einsum, IEEE divs,
// separately-rounded ufunc chain). DO NOT TOUCH.
__device__ __forceinline__ Samp px_chain(int w, int h, const float* th, float shn) {
    float bx = CX0 + fbar(GR * (float)w);
    float by = CY0 - fbar(GR * (float)h);

    float t00 = th[0], t01 = th[1], t02 = th[2];
    float t10 = th[3], t11 = th[4], t12 = th[5];
    float t20 = th[6], t21 = th[7], t22 = th[8];

    float g0 = fbar(__builtin_fmaf(by, t01, fbar(bx * t00))) + t02;
    float g1 = fbar(__builtin_fmaf(by, t11, fbar(bx * t10))) + t12;
    float g2 = fbar(__builtin_fmaf(by, t21, fbar(bx * t20))) + t22;

    float p0 = g0 / g2;
    float p1 = g1 / g2;

    float gx = fbar(p0 / 608.0f) - 1.0f;
    float gy = fbar((p1 - shn) / 144.0f) - 1.0f;

    float ix = (fbar((gx + 1.0f) * (float)Win) - 1.0f) * 0.5f;
    float iy = (fbar((gy + 1.0f) * (float)Hin) - 1.0f) * 0.5f;

    float ix0f = floorf(ix);
    float iy0f = floorf(iy);
    float wx = ix - ix0f;
    float wy = iy - iy0f;

    int x0 = (int)fminf(fmaxf(ix0f,        0.0f), (float)(Win - 1));
    int x1 = (int)fminf(fmaxf(ix0f + 1.0f, 0.0f), (float)(Win - 1));
    int y0 = (int)fminf(fmaxf(iy0f,        0.0f), (float)(Hin - 1));
    int y1 = (int)fminf(fmaxf(iy0f + 1.0f, 0.0f), (float)(Hin - 1));

    float omwx = 1.0f - wx;
    float omwy = 1.0f - wy;

    Samp s;
    s.w00 = omwx * omwy;
    s.w01 = wx * omwy;
    s.w10 = omwx * wy;
    s.w11 = wx * wy;

    int lo0 = y0 * Win + x0;
    int lo1 = y1 * Win + x0;
    s.lb0 = min(lo0, CH_STRIDE - 2);
    s.lb1 = min(lo1, CH_STRIDE - 2);
    s.hi0 = lo0 > s.lb0;
    s.hi1 = lo1 > s.lb1;
    s.xpair = x1 > x0;
    return s;
}

__device__ __forceinline__ float combine(float2 r0, float2 r1, const Samp& s) {
    float v00 = s.hi0   ? r0.y : r0.x;
    float v01 = s.xpair ? r0.y : v00;
    float v10 = s.hi1   ? r1.y : r1.x;
    float v11 = s.xpair ? r1.y : v10;
    return v00 * s.w00 + v01 * s.w01 + v10 * s.w10 + v11 * s.w11;
}

__global__ __launch_bounds__(BLK) void bev_sample_kernel(
    const float* __restrict__ x,      // (N, C, Hin, Win)
    const float* __restrict__ theta,  // (N, 3, 3)
    const float* __restrict__ shift,  // (N,)
    float* __restrict__ out)          // (N, C, Hout, Wout)
{
    // R15 winning body, ONE variable changed: 512-thread blocks (8 waves
    // per workgroup slot). Tests whether resident-wave count was capped by
    // WG slots (occupancy ~30% despite VGPR allowing 8 waves/SIMD).
    int gid = blockIdx.x * BLK + threadIdx.x;   // 0..HALF-1 (1250 blocks)

    // ---------------- pixel A ----------------
    int wA = gid % Wout;
    int tA = gid / Wout;
    int hA = tA % Hout;
    int nA = tA / Hout;
    int nAs = __builtin_amdgcn_readfirstlane(nA);

    Samp sA = px_chain(wA, hA, theta + nAs * 9, shift[nAs]);
    const float* xbA = x + (size_t)nAs * C * CH_STRIDE;

    float2 rA0[C], rA1[C];
    #pragma unroll
    for (int c = 0; c < C; ++c) {
        const float* p = xbA + (size_t)c * CH_STRIDE;
        rA0[c] = *reinterpret_cast<const float2*>(p + sA.lb0);
        rA1[c] = *reinterpret_cast<const float2*>(p + sA.lb1);
    }

    // ---------------- pixel B (chain overlaps A's loads) ----------------
    int pidB = gid + HALF;
    int wB = pidB % Wout;
    int tB = pidB / Wout;
    int hB = tB % Hout;
    int nB = tB / Hout;
    int nBs = __builtin_amdgcn_readfirstlane(nB);

    Samp sB = px_chain(wB, hB, theta + nBs * 9, shift[nBs]);
    const float* xbB = x + (size_t)nBs * C * CH_STRIDE;

    float2 rB0[C], rB1[C];
    #pragma unroll
    for (int c = 0; c < C; ++c) {
        const float* p = xbB + (size_t)c * CH_STRIDE;
        rB0[c] = *reinterpret_cast<const float2*>(p + sB.lb0);
        rB1[c] = *reinterpret_cast<const float2*>(p + sB.lb1);
    }

    // ---------------- combine + NT store A ----------------
    size_t obA = ((size_t)(nAs * C) * Hout + hA) * Wout + wA;
    #pragma unroll
    for (int c = 0; c < C; ++c) {
        float r = combine(rA0[c], rA1[c], sA);
        __builtin_nontemporal_store(r, &out[obA + (size_t)c * PIX_PER_N]);
    }

    // ---------------- combine + NT store B ----------------
    size_t obB = ((size_t)(nBs * C) * Hout + hB) * Wout + wB;
    #pragma unroll
    for (int c = 0; c < C; ++c) {
        float r = combine(rB0[c], rB1[c], sB);
        __builtin_nontemporal_store(r, &out[obB + (size_t)c * PIX_PER_N]);
    }
}

extern "C" void kernel_launch(void* const* d_in, const int* in_sizes, int n_in,
                              void* d_out, int out_size, void* d_ws, size_t ws_size,
                              hipStream_t stream) {
    const float* x     = (const float*)d_in[0];
    const float* theta = (const float*)d_in[1];
    const float* shift = (const float*)d_in[2];
    float* out = (float*)d_out;

    int blocks = HALF / BLK;                     // 1250, exact
    bev_sample_kernel<<<blocks, BLK, 0, stream>>>(x, theta, shift, out);
}

// Round 20
// 36.923 us; speedup vs baseline: 1.0541x; 1.0541x over previous
//
#include <hip/hip_runtime.h>
#include <math.h>

// Problem constants (fixed by setup_inputs)
constexpr int N    = 4;
constexpr int C    = 16;
constexpr int Hin  = 288;
constexpr int Win  = 1216;
constexpr int Hout = 800;
constexpr int Wout = 400;
constexpr int PIX_PER_N = Hout * Wout;       // 320000
constexpr int CH_STRIDE = Hin * Win;         // 350208
constexpr int TOTAL = N * Hout * Wout;       // 1,280,000
constexpr int HALF  = TOTAL / 2;             // 640,000

// Base-grid constants (exact reference f32 values; see round-6 derivation).
constexpr double grd = 0.05 * (800.0 / (double)Hout);        // 0.05 (f64)
constexpr float  GR  = (float)grd;                            // f32(0.05)
constexpr float  CX0 = (float)(-10.0 + grd / 2.0);            // f32(-9.975)
constexpr float  CY0 = (float)( 46.0 - grd / 2.0);            // f32(45.975)

// Register barrier: keeps ops separately rounded exactly where the numpy
// reference's ufuncs are separately rounded (correctness-critical near the
// g2~0 projective singularity). Coordinate chain ONLY.
__device__ __forceinline__ float fbar(float x) {
    asm volatile("" : "+v"(x));
    return x;
}

struct Samp {
    int   lb0, lb1;           // clamped dwordx2 load bases (row y0 / y1)
    bool  hi0, hi1, xpair;    // corner-select flags
    float w00, w01, w10, w11; // bilinear weights
};

// Bit-exact coordinate chain (verified round 6: flavor-F einsum, IEEE divs,
// separately-rounded ufunc chain). DO NOT TOUCH.
__device__ __forceinline__ Samp px_chain(int w, int h, const float* th, float shn) {
    float bx = CX0 + fbar(GR * (float)w);
    float by = CY0 - fbar(GR * (float)h);

    float t00 = th[0], t01 = th[1], t02 = th[2];
    float t10 = th[3], t11 = th[4], t12 = th[5];
    float t20 = th[6], t21 = th[7], t22 = th[8];

    float g0 = fbar(__builtin_fmaf(by, t01, fbar(bx * t00))) + t02;
    float g1 = fbar(__builtin_fmaf(by, t11, fbar(bx * t10))) + t12;
    float g2 = fbar(__builtin_fmaf(by, t21, fbar(bx * t20))) + t22;

    float p0 = g0 / g2;
    float p1 = g1 / g2;

    float gx = fbar(p0 / 608.0f) - 1.0f;
    float gy = fbar((p1 - shn) / 144.0f) - 1.0f;

    float ix = (fbar((gx + 1.0f) * (float)Win) - 1.0f) * 0.5f;
    float iy = (fbar((gy + 1.0f) * (float)Hin) - 1.0f) * 0.5f;

    float ix0f = floorf(ix);
    float iy0f = floorf(iy);
    float wx = ix - ix0f;
    float wy = iy - iy0f;

    int x0 = (int)fminf(fmaxf(ix0f,        0.0f), (float)(Win - 1));
    int x1 = (int)fminf(fmaxf(ix0f + 1.0f, 0.0f), (float)(Win - 1));
    int y0 = (int)fminf(fmaxf(iy0f,        0.0f), (float)(Hin - 1));
    int y1 = (int)fminf(fmaxf(iy0f + 1.0f, 0.0f), (float)(Hin - 1));

    float omwx = 1.0f - wx;
    float omwy = 1.0f - wy;

    Samp s;
    s.w00 = omwx * omwy;
    s.w01 = wx * omwy;
    s.w10 = omwx * wy;
    s.w11 = wx * wy;

    int lo0 = y0 * Win + x0;
    int lo1 = y1 * Win + x0;
    s.lb0 = min(lo0, CH_STRIDE - 2);
    s.lb1 = min(lo1, CH_STRIDE - 2);
    s.hi0 = lo0 > s.lb0;
    s.hi1 = lo1 > s.lb1;
    s.xpair = x1 > x0;
    return s;
}

__device__ __forceinline__ float combine(float2 r0, float2 r1, const Samp& s) {
    float v00 = s.hi0   ? r0.y : r0.x;
    float v01 = s.xpair ? r0.y : v00;
    float v10 = s.hi1   ? r1.y : r1.x;
    float v11 = s.xpair ? r1.y : v10;
    return v00 * s.w00 + v01 * s.w01 + v10 * s.w10 + v11 * s.w11;
}

__global__ __launch_bounds__(256) void bev_sample_kernel(
    const float* __restrict__ x,      // (N, C, Hin, Win)
    const float* __restrict__ theta,  // (N, 3, 3)
    const float* __restrict__ shift,  // (N,)
    float* __restrict__ out)          // (N, C, Hout, Wout)
{
    // R15 verbatim — the session's best configuration (36.8 us):
    // 2 px/thread (pid, pid+HALF), chainB overlaps A's load latency,
    // 64 loads in flight, separate dword NT stores, 2500 blocks.
    int gid = blockIdx.x * 256 + threadIdx.x;   // 0..HALF-1 (2500 blocks)

    // ---------------- pixel A ----------------
    int wA = gid % Wout;
    int tA = gid / Wout;
    int hA = tA % Hout;
    int nA = tA / Hout;
    int nAs = __builtin_amdgcn_readfirstlane(nA);

    Samp sA = px_chain(wA, hA, theta + nAs * 9, shift[nAs]);
    const float* xbA = x + (size_t)nAs * C * CH_STRIDE;

    float2 rA0[C], rA1[C];
    #pragma unroll
    for (int c = 0; c < C; ++c) {
        const float* p = xbA + (size_t)c * CH_STRIDE;
        rA0[c] = *reinterpret_cast<const float2*>(p + sA.lb0);
        rA1[c] = *reinterpret_cast<const float2*>(p + sA.lb1);
    }

    // ---------------- pixel B (chain overlaps A's loads) ----------------
    int pidB = gid + HALF;
    int wB = pidB % Wout;
    int tB = pidB / Wout;
    int hB = tB % Hout;
    int nB = tB / Hout;
    int nBs = __builtin_amdgcn_readfirstlane(nB);

    Samp sB = px_chain(wB, hB, theta + nBs * 9, shift[nBs]);
    const float* xbB = x + (size_t)nBs * C * CH_STRIDE;

    float2 rB0[C], rB1[C];
    #pragma unroll
    for (int c = 0; c < C; ++c) {
        const float* p = xbB + (size_t)c * CH_STRIDE;
        rB0[c] = *reinterpret_cast<const float2*>(p + sB.lb0);
        rB1[c] = *reinterpret_cast<const float2*>(p + sB.lb1);
    }

    // ---------------- combine + NT store A ----------------
    size_t obA = ((size_t)(nAs * C) * Hout + hA) * Wout + wA;
    #pragma unroll
    for (int c = 0; c < C; ++c) {
        float r = combine(rA0[c], rA1[c], sA);
        __builtin_nontemporal_store(r, &out[obA + (size_t)c * PIX_PER_N]);
    }

    // ---------------- combine + NT store B ----------------
    size_t obB = ((size_t)(nBs * C) * Hout + hB) * Wout + wB;
    #pragma unroll
    for (int c = 0; c < C; ++c) {
        float r = combine(rB0[c], rB1[c], sB);
        __builtin_nontemporal_store(r, &out[obB + (size_t)c * PIX_PER_N]);
    }
}

extern "C" void kernel_launch(void* const* d_in, const int* in_sizes, int n_in,
                              void* d_out, int out_size, void* d_ws, size_t ws_size,
                              hipStream_t stream) {
    const float* x     = (const float*)d_in[0];
    const float* theta = (const float*)d_in[1];
    const float* shift = (const float*)d_in[2];
    float* out = (float*)d_out;

    int blocks = HALF / 256;                     // 2500, exact
    bev_sample_kernel<<<blocks, 256, 0, stream>>>(x, theta, shift, out);
}